// Round 8
// baseline (138.439 us; speedup 1.0000x reference)
//
#include <hip/hip_runtime.h>

// vol [B=2, 192,192,192, C=1] fp32, affine [B,3,4] fp32,
// out [B,192,192,192,1] fp32.
#define DIM   192
#define PLANE (DIM * DIM)
#define NB    2
#define DPT   4   // d-voxels per thread (plane reuse in-thread, 16 loads/batch)
#define BH    4   // h rows per block

typedef float f2 __attribute__((ext_vector_type(2), aligned(4)));

// Ledger R0-R7: runtime == ~26cy x wave-VMEM-instr per CU, invariant to
// occupancy (R1), instr count 17-26 (R3/R5/R6), lines/wave 100-340 (R6),
// FETCH 27-75MB (R6/R7), XCD locality (R7: perfect L2 reuse, -44% fetch,
// +10% time). Everything behind L1 varied 2-3x with zero effect; everything
// in front under-saturated. Only remaining stage: L1/TCP per-instruction
// service. This round's decisive probe on the EXACT R0 structure (session
// best): nontemporal gathers bypass L1 -> straight to the shared 34.5TB/s
// L2. Same addresses, same arithmetic, bit-identical output. If neutral,
// the 26cy floor is TA-stage hardware and R0 is the gather roofline.
__global__ __launch_bounds__(256, 2) void
SpatialTransformer_warp_kernel(const float* __restrict__ vol,
                               const float* __restrict__ affine,
                               float* __restrict__ out) {
    const int tid = threadIdx.x;
    const int w   = (blockIdx.x << 6) + (tid & 63);   // 64-lane wave along w
    const int h   = blockIdx.y * BH + (tid >> 6);     // 4 h rows per block
    const int z   = blockIdx.z;                       // (d-quad | b)
    const int b   = (z >= DIM / DPT) ? 1 : 0;
    const int d0  = (z - b * (DIM / DPT)) * DPT;

    const float* __restrict__ A = affine + b * 12;
    const float a00 = A[0], a01 = A[1], a02 = A[2],  a03 = A[3];
    const float a10 = A[4], a11 = A[5], a12 = A[6],  a13 = A[7];
    const float a20 = A[8], a21 = A[9], a22 = A[10], a23 = A[11];

    const float center = (DIM - 1) * 0.5f;   // 95.5
    const float maxl   = (float)(DIM - 1);   // 191.0
    const float maxi0  = (float)(DIM - 2);   // 190.0
    const float fplane = (float)PLANE;       // 36864.0
    const float fdim   = (float)DIM;         // 192.0

    const float ch = (float)h - center;
    const float cw = (float)w - center;

    // Partial sums independent of d
    const float pd = a01 * ch + a02 * cw + a03 + center;
    const float ph = a11 * ch + a12 * cw + a13 + center;
    const float pw = a21 * ch + a22 * cw + a23 + center;

    const float* __restrict__ vb = vol + (size_t)b * DIM * PLANE;
    float* __restrict__ ob = out + ((size_t)b * DIM + d0) * PLANE
                                 + (size_t)h * DIM + w;

    f2 r00[DPT], r01[DPT], r10[DPT], r11[DPT];
    float w0d_[DPT], w0h_[DPT], w0w_[DPT];

    // ---- batch: compute all addresses, issue all 16 loads ----
#pragma unroll
    for (int k = 0; k < DPT; ++k) {
        const float cd = (float)(d0 + k) - center;
        const float ld = __builtin_fmaf(a00, cd, pd);
        const float lh = __builtin_fmaf(a10, cd, ph);
        const float lw = __builtin_fmaf(a20, cd, pw);

        // t = clamp(l,0,191); f = min(floor(t),190); i1 = f+1;
        // floor-corner weight = f+1-t  (reference semantics, R0-proven).
        const float td = __builtin_amdgcn_fmed3f(ld, 0.0f, maxl);
        const float th = __builtin_amdgcn_fmed3f(lh, 0.0f, maxl);
        const float tw = __builtin_amdgcn_fmed3f(lw, 0.0f, maxl);

        const float fd = fminf(floorf(td), maxi0);
        const float fh = fminf(floorf(th), maxi0);
        const float fw = fminf(floorf(tw), maxi0);

        w0d_[k] = fd + 1.0f - td;
        w0h_[k] = fh + 1.0f - th;
        w0w_[k] = fw + 1.0f - tw;

        // Flat index in float: integer-valued, < 2^24 -> exact.
        const int idx = (int)__builtin_fmaf(fd, fplane, __builtin_fmaf(fh, fdim, fw));
        const float* p = vb + idx;

        // Nontemporal: bypass L1 (the suspected per-instruction bottleneck),
        // service from the shared L2. Same data -> bit-identical results.
        r00[k] = __builtin_nontemporal_load((const f2*)(p));
        r01[k] = __builtin_nontemporal_load((const f2*)(p + DIM));
        r10[k] = __builtin_nontemporal_load((const f2*)(p + PLANE));
        r11[k] = __builtin_nontemporal_load((const f2*)(p + PLANE + DIM));
    }

    // Whole 16-load batch in flight, one drain.
    __builtin_amdgcn_sched_barrier(0);

    // ---- consume ----
#pragma unroll
    for (int k = 0; k < DPT; ++k) {
        const float w0w = w0w_[k], w1w = 1.0f - w0w;
        const float w0h = w0h_[k], w1h = 1.0f - w0h;
        const float w0d = w0d_[k], w1d = 1.0f - w0d;

        const float x00 = r00[k].x * w0w + r00[k].y * w1w;
        const float x01 = r01[k].x * w0w + r01[k].y * w1w;
        const float x10 = r10[k].x * w0w + r10[k].y * w1w;
        const float x11 = r11[k].x * w0w + r11[k].y * w1w;

        const float y0 = x00 * w0h + x01 * w1h;
        const float y1 = x10 * w0h + x11 * w1h;

        __builtin_nontemporal_store(y0 * w0d + y1 * w1d, ob + k * PLANE);
    }
}

extern "C" void kernel_launch(void* const* d_in, const int* in_sizes, int n_in,
                              void* d_out, int out_size, void* d_ws, size_t ws_size,
                              hipStream_t stream) {
    const float* vol    = (const float*)d_in[0];
    const float* affine = (const float*)d_in[1];
    float* out = (float*)d_out;

    dim3 grid(DIM / 64, DIM / BH, NB * (DIM / DPT));  // (w-tile, h-tile, d-quad|b)
    dim3 block(256);
    SpatialTransformer_warp_kernel<<<grid, block, 0, stream>>>(vol, affine, out);
}

// Round 9
// 126.002 us; speedup vs baseline: 1.0987x; 1.0987x over previous
//
#include <hip/hip_runtime.h>

// vol [B=2, 192,192,192, C=1] fp32, affine [B,3,4] fp32,
// out [B,192,192,192,1] fp32.
//
// FINAL (restore session best, R1): 47us kernel / ~123us harness.
//
// Why this is the floor (R0-R8 ledger): runtime is invariant to occupancy
// (37<->72%, R1), VMEM instruction count (17<->26, R3/R5/R6), cache-lines
// touched (R6), HBM fetch bytes (27-75MB, R6/R7); it gets WORSE with LDS
// staging (R2, 2.2x), perfect XCD/L2 locality (R7, +10%), and L1 bypass
// (R8, +8%). The binding resource is the per-CU texture-addressing stage:
// ~16cy per wave64 gather (64 divergent addrs @ ~4/cy), fixed-function,
// independent of where the data resides. Trilinear needs 4 row-segments
// per output (2x2x2 cube) -> 16 gathers per 4 outputs is algorithmically
// irreducible, and exec-masked sharing can't cut ISSUED instructions
// (P(any of 64 lanes diverges) ~= 1, proven in R3/R5).
#define DIM   192
#define PLANE (DIM * DIM)
#define NB    2
#define DPT   4   // d-voxels per thread (plane reuse in-thread, 16 loads/batch)
#define BH    4   // h rows per block

typedef float f2 __attribute__((ext_vector_type(2), aligned(4)));

__global__ __launch_bounds__(256) __attribute__((amdgpu_waves_per_eu(4, 4))) void
SpatialTransformer_warp_kernel(const float* __restrict__ vol,
                               const float* __restrict__ affine,
                               float* __restrict__ out) {
    const int tid = threadIdx.x;
    const int w   = (blockIdx.x << 6) + (tid & 63);   // 64-lane wave along w
    const int h   = blockIdx.y * BH + (tid >> 6);     // 4 h rows per block
    const int z   = blockIdx.z;                       // (d-quad | b)
    const int b   = (z >= DIM / DPT) ? 1 : 0;
    const int d0  = (z - b * (DIM / DPT)) * DPT;

    const float* __restrict__ A = affine + b * 12;
    const float a00 = A[0], a01 = A[1], a02 = A[2],  a03 = A[3];
    const float a10 = A[4], a11 = A[5], a12 = A[6],  a13 = A[7];
    const float a20 = A[8], a21 = A[9], a22 = A[10], a23 = A[11];

    const float center = (DIM - 1) * 0.5f;   // 95.5
    const float maxl   = (float)(DIM - 1);   // 191.0
    const float maxi0  = (float)(DIM - 2);   // 190.0
    const float fplane = (float)PLANE;       // 36864.0
    const float fdim   = (float)DIM;         // 192.0

    const float ch = (float)h - center;
    const float cw = (float)w - center;

    // Partial sums independent of d
    const float pd = a01 * ch + a02 * cw + a03 + center;
    const float ph = a11 * ch + a12 * cw + a13 + center;
    const float pw = a21 * ch + a22 * cw + a23 + center;

    const float* __restrict__ vb = vol + (size_t)b * DIM * PLANE;
    float* __restrict__ ob = out + ((size_t)b * DIM + d0) * PLANE
                                 + (size_t)h * DIM + w;

    f2 r00[DPT], r01[DPT], r10[DPT], r11[DPT];
    float w0d_[DPT], w0h_[DPT], w0w_[DPT];

    // ---- batch: compute all addresses, issue all 16 loads ----
#pragma unroll
    for (int k = 0; k < DPT; ++k) {
        const float cd = (float)(d0 + k) - center;
        const float ld = __builtin_fmaf(a00, cd, pd);
        const float lh = __builtin_fmaf(a10, cd, ph);
        const float lw = __builtin_fmaf(a20, cd, pw);

        // t = clamp(l,0,191); f = min(floor(t),190); i1 = f+1;
        // floor-corner weight = f+1-t  (reference semantics; right-clamped
        // corner has zero weight -> identical to the JAX reference).
        const float td = __builtin_amdgcn_fmed3f(ld, 0.0f, maxl);
        const float th = __builtin_amdgcn_fmed3f(lh, 0.0f, maxl);
        const float tw = __builtin_amdgcn_fmed3f(lw, 0.0f, maxl);

        const float fd = fminf(floorf(td), maxi0);
        const float fh = fminf(floorf(th), maxi0);
        const float fw = fminf(floorf(tw), maxi0);

        w0d_[k] = fd + 1.0f - td;
        w0h_[k] = fh + 1.0f - th;
        w0w_[k] = fw + 1.0f - tw;

        // Flat index in float: integer-valued, < 2^24 -> exact.
        const int idx = (int)__builtin_fmaf(fd, fplane, __builtin_fmaf(fh, fdim, fw));
        const float* p = vb + idx;

        r00[k] = *(const f2*)(p);                   // (fd,   fh,   fw..fw+1)
        r01[k] = *(const f2*)(p + DIM);             // (fd,   fh+1)
        r10[k] = *(const f2*)(p + PLANE);           // (fd+1, fh)
        r11[k] = *(const f2*)(p + PLANE + DIM);     // (fd+1, fh+1)
    }

    // Whole 16-load batch in flight, one drain.
    __builtin_amdgcn_sched_barrier(0);

    // ---- consume ----
#pragma unroll
    for (int k = 0; k < DPT; ++k) {
        const float w0w = w0w_[k], w1w = 1.0f - w0w;
        const float w0h = w0h_[k], w1h = 1.0f - w0h;
        const float w0d = w0d_[k], w1d = 1.0f - w0d;

        const float x00 = r00[k].x * w0w + r00[k].y * w1w;
        const float x01 = r01[k].x * w0w + r01[k].y * w1w;
        const float x10 = r10[k].x * w0w + r10[k].y * w1w;
        const float x11 = r11[k].x * w0w + r11[k].y * w1w;

        const float y0 = x00 * w0h + x01 * w1h;
        const float y1 = x10 * w0h + x11 * w1h;

        __builtin_nontemporal_store(y0 * w0d + y1 * w1d, ob + k * PLANE);
    }
}

extern "C" void kernel_launch(void* const* d_in, const int* in_sizes, int n_in,
                              void* d_out, int out_size, void* d_ws, size_t ws_size,
                              hipStream_t stream) {
    const float* vol    = (const float*)d_in[0];
    const float* affine = (const float*)d_in[1];
    float* out = (float*)d_out;

    dim3 grid(DIM / 64, DIM / BH, NB * (DIM / DPT));  // (w-tile, h-tile, d-quad|b)
    dim3 block(256);
    SpatialTransformer_warp_kernel<<<grid, block, 0, stream>>>(vol, affine, out);
}